// Round 16
// baseline (177.389 us; speedup 1.0000x reference)
//
#include <hip/hip_runtime.h>
#include <hip/hip_bf16.h>
#include <hip/hip_cooperative_groups.h>

namespace cg = cooperative_groups;

constexpr int Bb  = 8;
constexpr int Nn  = 2048;
constexpr int FIN = 128;
constexpr int FOUT = 64;
constexpr float LOG2E = 1.4426950408889634f;

typedef __bf16 bf16x8 __attribute__((ext_vector_type(8)));
typedef __bf16 bf16x2 __attribute__((ext_vector_type(2)));
typedef float  f32x4  __attribute__((ext_vector_type(4)));
typedef int    i32x4  __attribute__((ext_vector_type(4)));
typedef unsigned int u32;

__device__ __forceinline__ u32 f2bf_bits(float f) {
    u32 u = __builtin_bit_cast(u32, f);
    return (u + 0x7FFFu + ((u >> 16) & 1u)) >> 16;  // RNE
}

// ---- Phase-1 body: k1 work for 16 rows [i0, i0+16) of batch b, 4 rows/wave.
// Writes whfrag (global), fd (global), fs (global AND block-local LDS).
__device__ __forceinline__ void k1_body(
        const float* __restrict__ h, const float* __restrict__ W,
        const float* __restrict__ a, __bf16* __restrict__ whfrag,
        float* __restrict__ fsg, float* __restrict__ fd, float* fs_lds,
        float (*hT)[FIN], int b, int i0, int l, int w, int tid) {
    {
        const float4* hb = reinterpret_cast<const float4*>(h + (size_t)(b * Nn + i0) * FIN);
        float4* dst = reinterpret_cast<float4*>(&hT[0][0]);
        dst[tid]       = hb[tid];
        dst[tid + 256] = hb[tid + 256];
    }
    __syncthreads();

    const float a0 = a[l];
    const float a1 = a[FOUT + l];

    float acc[4];
#pragma unroll
    for (int r = 0; r < 4; ++r) acc[r] = 0.f;

#pragma unroll 1
    for (int c0 = 0; c0 < FIN; c0 += 32) {
        float wreg[32];
#pragma unroll
        for (int cc = 0; cc < 32; ++cc) wreg[cc] = W[(c0 + cc) * FOUT + l];
#pragma unroll
        for (int r = 0; r < 4; ++r) {
            const int row = w * 4 + r;
#pragma unroll
            for (int cc = 0; cc < 32; ++cc)
                acc[r] = fmaf(hT[row][c0 + cc], wreg[cc], acc[r]);  // LDS broadcast
        }
    }

#pragma unroll
    for (int r = 0; r < 4; ++r) {
        float s0 = acc[r] * a0;
        float s1 = acc[r] * a1;
#pragma unroll
        for (int off = 32; off >= 1; off >>= 1) {
            s0 += __shfl_xor(s0, off, 64);
            s1 += __shfl_xor(s1, off, 64);
        }
        if (l == 0) {
            fs_lds[w * 4 + r] = s0 * LOG2E;
            fsg[b * Nn + i0 + w * 4 + r] = s0 * LOG2E;
            fd [b * Nn + i0 + w * 4 + r] = s1 * LOG2E;
        }
    }

    // pack 4 rows into half a B-frag slot (rows rseg=(w&1)*4+0..3 of the 8-row seg)
    const u32 pk0 = f2bf_bits(acc[0]) | (f2bf_bits(acc[1]) << 16);
    const u32 pk1 = f2bf_bits(acc[2]) | (f2bf_bits(acc[3]) << 16);
    const int t32  = i0 >> 5;
    const int half = (i0 >> 4) & 1;
    const int Lc   = ((half * 2 + (w >> 1)) << 4) | (l & 15);
    const int slot = ((b * 64 + t32) * 4 + (l >> 4)) * 64 + Lc;
    *reinterpret_cast<uint2*>(reinterpret_cast<char*>(whfrag)
                              + (size_t)slot * 16 + (w & 1) * 8) = make_uint2(pk0, pk1);
}

// ---- Phase-2 body: EXACT r8 champion k2 main loop + epilogue.
// adjR slots 0,1 must be pre-loaded by the caller (enables pre-sync prefetch).
__device__ __forceinline__ void k2_body(
        const int* __restrict__ adj0, const float* __restrict__ fdp,
        const bf16x8* __restrict__ bfr, const float fs_loc[4],
        char* myA, f32x4 (*comb)[4][64], float (*zpart)[16],
        float* __restrict__ out, int b, int i0, int l, int w, int g, int jc,
        i32x4 (&adjR)[3][4]) {
    f32x4 acc[4] = {{0,0,0,0},{0,0,0,0},{0,0,0,0},{0,0,0,0}};
    f32x4 accz   = {0.f, 0.f, 0.f, 0.f};

    bf16x8 onesv;
#pragma unroll
    for (int i = 0; i < 8; ++i) onesv[i] = (__bf16)1.0f;

    f32x4 fdR[3];
    fdR[0] = *reinterpret_cast<const f32x4*>(fdp);
    fdR[1] = *reinterpret_cast<const f32x4*>(fdp + 64);

#define GAT_STEP(IT, CUR, PRE)                                                 \
  {                                                                            \
    if ((IT) + 2 < 8) {                                                        \
      _Pragma("unroll")                                                        \
      for (int rr = 0; rr < 4; ++rr)                                           \
        adjR[PRE][rr] = *reinterpret_cast<const i32x4*>(                       \
            adj0 + (size_t)rr * Nn + ((IT) + 2) * 64);                         \
      fdR[PRE] = *reinterpret_cast<const f32x4*>(fdp + ((IT) + 2) * 64);       \
    }                                                                          \
    char* buf = myA + ((IT) & 1) * 2048;                                       \
    _Pragma("unroll")                                                          \
    for (int rr = 0; rr < 4; ++rr) {                                           \
      const int row = g * 4 + rr;                                              \
      u32 wds[2];                                                              \
      _Pragma("unroll")                                                        \
      for (int hp = 0; hp < 2; ++hp) {                                         \
        float pv[2];                                                           \
        _Pragma("unroll")                                                      \
        for (int q = 0; q < 2; ++q) {                                          \
          const int jj = hp * 2 + q;                                           \
          float e  = fs_loc[rr] + fdR[CUR][jj];                                \
          float lr = fmaxf(e, 0.2f * e);       /* leaky relu (scale-safe) */   \
          float p  = exp2f(lr);                /* fs/fd pre-scaled by log2e */ \
          pv[q] = (adjR[CUR][rr][jj] > 0) ? p : 0.f;                           \
        }                                                                      \
        wds[hp] = __builtin_bit_cast(u32,                                      \
                      (bf16x2){(__bf16)pv[0], (__bf16)pv[1]});                 \
      }                                                                        \
      const int boff = (row * 128 + jc * 8) ^ ((row & 7) << 4);                \
      *reinterpret_cast<uint2*>(buf + boff) = make_uint2(wds[0], wds[1]);      \
    }                                                                          \
    asm volatile("s_waitcnt lgkmcnt(0)" ::: "memory");                         \
    __builtin_amdgcn_sched_barrier(0x20);   /* VMEM reads may hoist */         \
    {                                                                          \
      const int rb0 = (((l & 15) * 128 + g * 16) ^ ((l & 7) << 4));            \
      bf16x8 av = *reinterpret_cast<const bf16x8*>(buf + rb0);                 \
      _Pragma("unroll")                                                        \
      for (int o16 = 0; o16 < 4; ++o16)                                        \
        acc[o16] = __builtin_amdgcn_mfma_f32_16x16x32_bf16(                    \
            av, bfr[(((IT) * 2 + 0) * 4 + o16) * 64], acc[o16], 0, 0, 0);      \
      accz = __builtin_amdgcn_mfma_f32_16x16x32_bf16(av, onesv, accz, 0, 0, 0);\
    }                                                                          \
    {                                                                          \
      const int rb1 = (((l & 15) * 128 + 64 + g * 16) ^ ((l & 7) << 4));       \
      bf16x8 av = *reinterpret_cast<const bf16x8*>(buf + rb1);                 \
      _Pragma("unroll")                                                        \
      for (int o16 = 0; o16 < 4; ++o16)                                        \
        acc[o16] = __builtin_amdgcn_mfma_f32_16x16x32_bf16(                    \
            av, bfr[(((IT) * 2 + 1) * 4 + o16) * 64], acc[o16], 0, 0, 0);      \
      accz = __builtin_amdgcn_mfma_f32_16x16x32_bf16(av, onesv, accz, 0, 0, 0);\
    }                                                                          \
  }

    GAT_STEP(0, 0, 2)
    GAT_STEP(1, 1, 0)
    GAT_STEP(2, 2, 1)
    GAT_STEP(3, 0, 2)
    GAT_STEP(4, 1, 0)
    GAT_STEP(5, 2, 1)
    GAT_STEP(6, 0, 2)
    GAT_STEP(7, 1, 0)
#undef GAT_STEP

    if ((l & 15) == 0) {
#pragma unroll
        for (int r = 0; r < 4; ++r) zpart[w][(l >> 4) * 4 + r] = accz[r];
    }
#pragma unroll
    for (int o16 = 0; o16 < 4; ++o16) comb[w][o16][l] = acc[o16];
    __syncthreads();

    f32x4 res = comb[0][w][l];
#pragma unroll
    for (int wp = 1; wp < 4; ++wp) res += comb[wp][w][l];

#pragma unroll
    for (int r = 0; r < 4; ++r) {
        const int row = g * 4 + r;                     // C/D: row=(l>>4)*4+r, col=l&15
        float z = zpart[0][row] + zpart[1][row] + zpart[2][row] + zpart[3][row];
        float v = res[r] / z;
        v = v > 0.f ? v : expm1f(v);                   // ELU
        out[(size_t)(b * Nn + i0 + row) * FOUT + w * 16 + jc] = v;
    }
}

// ---- Fused cooperative kernel: phase1 -> adj prefetch -> grid.sync -> phase2.
// b = blk&7 puts each batch on one XCD (whfrag/fd L2-private, producer==consumer XCD).
__global__ __launch_bounds__(256, 4) void gat_fused(
        const float* __restrict__ h, const int* __restrict__ adj,
        const float* __restrict__ W, const float* __restrict__ a,
        __bf16* __restrict__ whfrag, float* __restrict__ fsg,
        float* __restrict__ fd, float* __restrict__ out) {
    __shared__ __align__(16) char  aLDS[4 * 4096];
    __shared__ __align__(16) f32x4 comb[4][4][64];    // phase1 aliases first 8 KB as hT
    __shared__ float zpart[4][16];
    __shared__ float fs_lds[16];

    const int blk = blockIdx.x;              // 1024
    const int b   = blk & 7;                 // XCD-local batch
    const int i0  = (blk >> 3) * 16;
    const int l   = threadIdx.x & 63;
    const int w   = __builtin_amdgcn_readfirstlane((int)(threadIdx.x >> 6));

    float (*hT)[FIN] = reinterpret_cast<float(*)[FIN]>(&comb[0][0][0]);
    k1_body(h, W, a, whfrag, fsg, fd, fs_lds, hT, b, i0, l, w, (int)threadIdx.x);

    // prefetch first two adj tiles BEFORE the grid barrier (adj is an input)
    const int g = l >> 4, jc = l & 15;
    const int* adj0 = adj + (size_t)(b * Nn + i0 + g * 4) * Nn + w * 512 + jc * 4;
    i32x4 adjR[3][4];
#pragma unroll
    for (int rr = 0; rr < 4; ++rr) {
        adjR[0][rr] = *reinterpret_cast<const i32x4*>(adj0 + (size_t)rr * Nn);
        adjR[1][rr] = *reinterpret_cast<const i32x4*>(adj0 + (size_t)rr * Nn + 64);
    }

    cg::this_grid().sync();   // whfrag/fd from all blocks now visible

    float fs_loc[4];
#pragma unroll
    for (int rr = 0; rr < 4; ++rr) fs_loc[rr] = fs_lds[g * 4 + rr];
    const float* fdp = fd + b * Nn + w * 512 + jc * 4;
    const bf16x8* bfr = reinterpret_cast<const bf16x8*>(whfrag)
                        + (size_t)((b * 64 + w * 16) * 4) * 64 + l;

    k2_body(adj0, fdp, bfr, fs_loc, aLDS + w * 4096, comb, zpart, out,
            b, i0, l, w, g, jc, adjR);
}

// ---- Fallback pair (identical math) if cooperative launch is unavailable ----
__global__ __launch_bounds__(256) void gat_k1_fast(
        const float* __restrict__ h, const float* __restrict__ W,
        const float* __restrict__ a, __bf16* __restrict__ whfrag,
        float* __restrict__ fsg, float* __restrict__ fd) {
    __shared__ __align__(16) float hT[16][FIN];   // 8 KB
    __shared__ float fs_lds[16];
    const int blk = blockIdx.x;
    const int b   = blk & 7;
    const int i0  = (blk >> 3) * 16;
    const int l   = threadIdx.x & 63;
    const int w   = __builtin_amdgcn_readfirstlane((int)(threadIdx.x >> 6));
    k1_body(h, W, a, whfrag, fsg, fd, fs_lds, hT, b, i0, l, w, (int)threadIdx.x);
}

__global__ __launch_bounds__(256, 4) void gat_k2(
        const int* __restrict__ adj, const __bf16* __restrict__ whfrag,
        const float* __restrict__ fsg, const float* __restrict__ fd,
        float* __restrict__ out) {
    __shared__ __align__(16) char  aLDS[4 * 4096];
    __shared__ __align__(16) f32x4 comb[4][4][64];
    __shared__ float zpart[4][16];

    const int blk = blockIdx.x;
    const int b   = blk & 7;
    const int i0  = (blk >> 3) * 16;
    const int l   = threadIdx.x & 63;
    const int w   = __builtin_amdgcn_readfirstlane((int)(threadIdx.x >> 6));

    const int g = l >> 4, jc = l & 15;
    const int* adj0 = adj + (size_t)(b * Nn + i0 + g * 4) * Nn + w * 512 + jc * 4;
    i32x4 adjR[3][4];
#pragma unroll
    for (int rr = 0; rr < 4; ++rr) {
        adjR[0][rr] = *reinterpret_cast<const i32x4*>(adj0 + (size_t)rr * Nn);
        adjR[1][rr] = *reinterpret_cast<const i32x4*>(adj0 + (size_t)rr * Nn + 64);
    }

    float fs_loc[4];
#pragma unroll
    for (int rr = 0; rr < 4; ++rr) fs_loc[rr] = fsg[b * Nn + i0 + g * 4 + rr];
    const float* fdp = fd + b * Nn + w * 512 + jc * 4;
    const bf16x8* bfr = reinterpret_cast<const bf16x8*>(whfrag)
                        + (size_t)((b * 64 + w * 16) * 4) * 64 + l;

    k2_body(adj0, fdp, bfr, fs_loc, aLDS + w * 4096, comb, zpart, out,
            b, i0, l, w, g, jc, adjR);
}

extern "C" void kernel_launch(void* const* d_in, const int* in_sizes, int n_in,
                              void* d_out, int out_size, void* d_ws, size_t ws_size,
                              hipStream_t stream) {
    const float* h   = (const float*)d_in[0];
    const int*   adj = (const int*)d_in[1];
    const float* W   = (const float*)d_in[2];
    const float* a   = (const float*)d_in[3];
    float* out = (float*)d_out;

    __bf16* whfrag = (__bf16*)d_ws;                                   // 2 MB
    float*  fsg    = (float*)((char*)d_ws + (size_t)Bb * Nn * FOUT * 2);
    float*  fd     = fsg + Bb * Nn;

    void* kargs[] = { (void*)&h, (void*)&adj, (void*)&W, (void*)&a,
                      (void*)&whfrag, (void*)&fsg, (void*)&fd, (void*)&out };
    hipError_t e = hipLaunchCooperativeKernel(
        reinterpret_cast<void*>(gat_fused), dim3(1024), dim3(256), kargs, 0, stream);
    if (e != hipSuccess) {
        // graceful fallback: identical math, two dispatches
        gat_k1_fast<<<dim3(1024), dim3(256), 0, stream>>>(h, W, a, whfrag, fsg, fd);
        gat_k2    <<<dim3(1024), dim3(256), 0, stream>>>(adj, whfrag, fsg, fd, out);
    }
}